// Round 6
// baseline (711.139 us; speedup 1.0000x reference)
//
#include <hip/hip_runtime.h>
#include <math.h>

static constexpr float F0        = 0.17677669529663687f;  // 1/sqrt(32)
static constexpr float SILU_GAIN = 1.6791f;
static constexpr float INV_SQ3   = 0.5773502691896258f;   // 1/sqrt(3)
static constexpr float INV_SQ2   = 0.7071067811865475f;   // 1/sqrt(2)
static constexpr float C_S       = 0.3826834323650898f;   // sin(pi/8)
static constexpr float C_X       = 0.9238795325112867f;   // cos(pi/8)
static constexpr float INV_SQRT_NN = 0.25f;
static constexpr float INV8      = 0.125f;                // 1/8 (and 1/sqrt(64))
static constexpr float INV_SQ96  = 0.10206207261596575f;  // 1/sqrt(96)

// Wave-synchronous LDS sync: program-order pin for the compiler (memory clobber)
// + scheduling barrier. Per-wave DS-pipe in-order execution provides the HW side.
#define WAVE_SYNC() do { asm volatile("" ::: "memory"); \
                         __builtin_amdgcn_wave_barrier(); \
                         asm volatile("" ::: "memory"); } while (0)

// ---------------- K1: per-node linear transforms (grid-strided) ----------------
// out[n][0:128]  = C_S * F0 * na * (xs@Wsc0 | xv@Wsc1)      (self path, pre-scaled)
// l_sv[n][0:128] =        F0 * na * (xs@Wl10 | xv@Wl11)     (gathered by edges)
__global__ __launch_bounds__(256) void k_node(
    const float* __restrict__ node_input, const float* __restrict__ node_attr,
    const float* __restrict__ Wsc0, const float* __restrict__ Wsc1,
    const float* __restrict__ Wl10, const float* __restrict__ Wl11,
    float* __restrict__ out, float* __restrict__ l_sv, int N)
{
    __shared__ float sW[4][32][32];          // Wsc0, Wsc1, Wl10, Wl11
    __shared__ __align__(16) float sX[4][128];
    int tid = threadIdx.x;
    float4* sWv = (float4*)&sW[0][0][0];
    for (int i = tid; i < 256; i += 256) {   // 1024 floats per matrix = 256 float4
        sWv[i]       = ((const float4*)Wsc0)[i];
        sWv[256+i]   = ((const float4*)Wsc1)[i];
        sWv[512+i]   = ((const float4*)Wl10)[i];
        sWv[768+i]   = ((const float4*)Wl11)[i];
    }
    __syncthreads();
    int wave = tid >> 6, lane = tid & 63;
    int ngroups = (N + 3) >> 2;

    for (int grp = blockIdx.x; grp < ngroups; grp += gridDim.x) {
        int node = grp * 4 + wave;
        if (node >= N) continue;

        float2 v = *(const float2*)&node_input[(size_t)node*128 + lane*2];
        sX[wave][lane*2]   = v.x;
        sX[wave][lane*2+1] = v.y;
        float na = node_attr[node];
        WAVE_SYNC();

        const float* X = sX[wave];
        float g = F0 * na;
        #pragma unroll
        for (int p = 0; p < 2; p++) {
            int o = lane + p*64;
            float vs = 0.f, vl = 0.f;
            if (o < 32) {
                #pragma unroll
                for (int u = 0; u < 32; u++) {
                    float x = X[u];
                    vs = fmaf(x, sW[0][u][o], vs);
                    vl = fmaf(x, sW[2][u][o], vl);
                }
            } else {
                int f = o - 32; int w = f / 3; int i3 = f - 3*w;
                #pragma unroll
                for (int u = 0; u < 32; u++) {
                    float x = X[32 + 3*u + i3];
                    vs = fmaf(x, sW[1][u][w], vs);
                    vl = fmaf(x, sW[3][u][w], vl);
                }
            }
            out [(size_t)node*128 + o] = C_S * g * vs;
            l_sv[(size_t)node*128 + o] = g * vl;
        }
        WAVE_SYNC();   // sX reuse guard
    }
}

// ---------------- CSR build ----------------
__global__ void k_hist(const int* __restrict__ ei, int* __restrict__ deg, int E) {
    int e = blockIdx.x*256 + threadIdx.x;
    if (e < E) atomicAdd(&deg[ei[E + e]], 1);
}

__global__ void k_scan_part(const int* __restrict__ deg, int* __restrict__ offs,
                            int* __restrict__ part, int n) {
    __shared__ int tmp[1024];
    int t = threadIdx.x, i = blockIdx.x*1024 + t;
    int v = (i < n) ? deg[i] : 0;
    tmp[t] = v; __syncthreads();
    for (int d = 1; d < 1024; d <<= 1) {
        int x = (t >= d) ? tmp[t-d] : 0;
        __syncthreads();
        tmp[t] += x;
        __syncthreads();
    }
    if (i < n) offs[i] = tmp[t] - v;           // block-local exclusive
    if (t == 1023) part[blockIdx.x] = tmp[1023];
}

__global__ void k_scan_top(int* part, int* offs, int nb, int n) {
    if (threadIdx.x == 0 && blockIdx.x == 0) {
        int run = 0;
        for (int b = 0; b < nb; b++) { int v = part[b]; part[b] = run; run += v; }
        offs[n] = run;                          // == E
    }
}

__global__ void k_scan_add(int* offs, const int* part, int n) {
    int i = blockIdx.x*256 + threadIdx.x;
    if (i < n) offs[i] += part[i >> 10];
}

__global__ void k_fill(const int* __restrict__ ei, const int* __restrict__ offs,
                       int* __restrict__ cur, int* __restrict__ elist, int E) {
    int e = blockIdx.x*256 + threadIdx.x;
    if (e < E) {
        int d = ei[E + e];
        int p = atomicAdd(&cur[d], 1);
        elist[offs[d] + p] = e;
    }
}

// ---------------- K2: wave-per-node edge aggregation (grid-strided) ----------------
// LDS budget: sWfc1 40KB + sH 8KB + sES 2KB + sEA/sSRC ~0.6KB = 50.6KB -> 3 blocks/CU
// (= 3 waves/SIMD at 256 threads). Wfc0 lives in 16 VGPRs (per-lane column);
// W20/W21 (20KB) read from global -> L1-resident after first node.
__global__ __launch_bounds__(256, 3) void k_edge(
    const int*   __restrict__ ei,           // 2*E (src | dst)
    const float* __restrict__ edge_attr,    // E x 4
    const float* __restrict__ edge_scalars, // E x 16
    const float* __restrict__ Wfc0,         // 16 x 64
    const float* __restrict__ Wfc1,         // 64 x 160
    const float* __restrict__ W20,          // 64 x 32
    const float* __restrict__ W21,          // 96 x 32
    const float* __restrict__ node_attr,
    const float* __restrict__ l_sv,
    const int*   __restrict__ offs,
    const int*   __restrict__ elist,
    float* __restrict__ out, int N, int E)
{
    __shared__ float sWfc1[64][160];             // 40 KB  (col%32 -> 2 lanes/bank, free)
    __shared__ __align__(16) float sH [4][8][64];// 8 KB  (h per edge; reused as epilogue scratch)
    __shared__ __align__(16) float sES[4][8][16];// 2 KB
    __shared__ float sEA[4][8][4];
    __shared__ int   sSRC[4][8];

    int tid = threadIdx.x;
    {   // 10240 floats = 2560 float4
        float4* dst = (float4*)&sWfc1[0][0];
        const float4* src = (const float4*)Wfc1;
        for (int i = tid; i < 2560; i += 256) dst[i] = src[i];
    }

    int wave = tid >> 6, lane = tid & 63;
    int half = lane >> 5, u = lane & 31;

    // Wfc0 column for this lane: 16 registers, reused for every edge.
    float wfc0_r[16];
    #pragma unroll
    for (int i = 0; i < 16; i++) wfc0_r[i] = Wfc0[i*64 + lane];

    __syncthreads();

    int ngroups = (N + 3) >> 2;

    for (int grp = blockIdx.x; grp < ngroups; grp += gridDim.x) {
        int node = grp * 4 + wave;
        if (node >= N) continue;

        int e0 = offs[node], e1 = offs[node+1];
        int cnt_all = e1 - e0;
        const int* mylist = elist + e0;
        float na = node_attr[node];          // issued early: latency hides under edge loop

        float a0 = 0.f, a1 = 0.f;
        float av0[3] = {0,0,0}, av1[3] = {0,0,0}, av2[3] = {0,0,0};

        for (int base = 0; base < cnt_all; base += 8) {
            int cnt = cnt_all - base; if (cnt > 8) cnt = 8;

            // ---- stage edge meta + edge_scalars into LDS ----
            if (lane < 8) {
                bool val = lane < cnt;
                int eid = val ? mylist[base + lane] : 0;
                sSRC[wave][lane] = val ? ei[eid] : 0;
                float4 ea = val ? *(const float4*)&edge_attr[(size_t)eid*4] : make_float4(0,0,0,0);
                sEA[wave][lane][0] = ea.x; sEA[wave][lane][1] = ea.y;
                sEA[wave][lane][2] = ea.z; sEA[wave][lane][3] = ea.w;
            }
            {
                int e = lane >> 3, i2 = (lane & 7) << 1;
                bool val = e < cnt;
                int eid = val ? mylist[base + e] : 0;
                float2 v = val ? *(const float2*)&edge_scalars[(size_t)eid*16 + i2] : make_float2(0,0);
                sES[wave][e][i2]   = v.x;
                sES[wave][e][i2+1] = v.y;
            }
            WAVE_SYNC();

            // ---- gather prefetch: issue l_sv loads for this chunk's edges NOW so
            // their ~200-900cy latency hides under phase 1+2 VALU work (~2800cy).
            float xs_r[4], xv_r[4][3];
            #pragma unroll
            for (int t = 0; t < 4; t++) {
                int srcn = sSRC[wave][half*4 + t];
                const float* lp = l_sv + (size_t)srcn * 128;
                xs_r[t]    = lp[u];
                xv_r[t][0] = lp[32 + 3*u];
                xv_r[t][1] = lp[33 + 3*u];
                xv_r[t][2] = lp[34 + 3*u];
            }

            // ---- phase 1: h[e][lane] = SILU_GAIN * silu(es@Wfc0 / 4) ----
            #pragma unroll
            for (int e = 0; e < 8; e++) {
                float s = 0.f;
                const float4* esv = (const float4*)sES[wave][e];
                #pragma unroll
                for (int i4 = 0; i4 < 4; i4++) {
                    float4 ev = esv[i4];
                    s = fmaf(ev.x, wfc0_r[i4*4+0], s);
                    s = fmaf(ev.y, wfc0_r[i4*4+1], s);
                    s = fmaf(ev.z, wfc0_r[i4*4+2], s);
                    s = fmaf(ev.w, wfc0_r[i4*4+3], s);
                }
                s *= 0.25f;
                sH[wave][e][lane] = SILU_GAIN * s / (1.f + __expf(-s));
            }
            WAVE_SYNC();

            // ---- phase 2: lane (half,u) computes w0..w4[u] for its 4 edges ----
            float w0[4] = {0,0,0,0}, w1[4] = {0,0,0,0}, w2[4] = {0,0,0,0};
            float w3[4] = {0,0,0,0}, w4[4] = {0,0,0,0};
            #pragma unroll 2
            for (int j = 0; j < 64; j += 4) {
                float4 hv0 = *(const float4*)&sH[wave][half*4+0][j];
                float4 hv1 = *(const float4*)&sH[wave][half*4+1][j];
                float4 hv2 = *(const float4*)&sH[wave][half*4+2][j];
                float4 hv3 = *(const float4*)&sH[wave][half*4+3][j];
                float h0[4] = {hv0.x, hv0.y, hv0.z, hv0.w};
                float h1[4] = {hv1.x, hv1.y, hv1.z, hv1.w};
                float h2[4] = {hv2.x, hv2.y, hv2.z, hv2.w};
                float h3[4] = {hv3.x, hv3.y, hv3.z, hv3.w};
                #pragma unroll
                for (int jj = 0; jj < 4; jj++) {
                    float c0 = sWfc1[j+jj][u];
                    float c1 = sWfc1[j+jj][32+u];
                    float c2 = sWfc1[j+jj][64+u];
                    float c3 = sWfc1[j+jj][96+u];
                    float c4 = sWfc1[j+jj][128+u];
                    w0[0]=fmaf(h0[jj],c0,w0[0]); w1[0]=fmaf(h0[jj],c1,w1[0]); w2[0]=fmaf(h0[jj],c2,w2[0]); w3[0]=fmaf(h0[jj],c3,w3[0]); w4[0]=fmaf(h0[jj],c4,w4[0]);
                    w0[1]=fmaf(h1[jj],c0,w0[1]); w1[1]=fmaf(h1[jj],c1,w1[1]); w2[1]=fmaf(h1[jj],c2,w2[1]); w3[1]=fmaf(h1[jj],c3,w3[1]); w4[1]=fmaf(h1[jj],c4,w4[1]);
                    w0[2]=fmaf(h2[jj],c0,w0[2]); w1[2]=fmaf(h2[jj],c1,w1[2]); w2[2]=fmaf(h2[jj],c2,w2[2]); w3[2]=fmaf(h2[jj],c3,w3[2]); w4[2]=fmaf(h2[jj],c4,w4[2]);
                    w0[3]=fmaf(h3[jj],c0,w0[3]); w1[3]=fmaf(h3[jj],c1,w1[3]); w2[3]=fmaf(h3[jj],c2,w2[3]); w3[3]=fmaf(h3[jj],c3,w3[3]); w4[3]=fmaf(h3[jj],c4,w4[3]);
                }
            }

            // ---- phase 3: mids + accumulate (invalid edges have w==0) ----
            #pragma unroll
            for (int t = 0; t < 4; t++) {
                int ee = half*4 + t;
                float ea0 = sEA[wave][ee][0];
                float ev0 = sEA[wave][ee][1], ev1 = sEA[wave][ee][2], ev2 = sEA[wave][ee][3];
                float xs  = xs_r[t];
                float xv0 = xv_r[t][0], xv1 = xv_r[t][1], xv2 = xv_r[t][2];
                float W0 = w0[t]*INV8, W1 = w1[t]*INV8, W2 = w2[t]*INV8;
                float W3 = w3[t]*INV8, W4 = w4[t]*INV8;

                a0 = fmaf(W0 * ea0, xs, a0);                       // mid0
                float dv = fmaf(xv0, ev0, fmaf(xv1, ev1, xv2*ev2));
                a1 = fmaf(W3 * INV_SQ3, dv, a1);                   // mid1
                float t1 = W1 * xs;                                 // mid2
                av0[0] = fmaf(t1, ev0, av0[0]); av0[1] = fmaf(t1, ev1, av0[1]); av0[2] = fmaf(t1, ev2, av0[2]);
                float t2 = W2 * ea0;                                // mid3
                av1[0] = fmaf(t2, xv0, av1[0]); av1[1] = fmaf(t2, xv1, av1[1]); av1[2] = fmaf(t2, xv2, av1[2]);
                float cr0 = xv1*ev2 - xv2*ev1;                      // mid4 (cross)
                float cr1 = xv2*ev0 - xv0*ev2;
                float cr2 = xv0*ev1 - xv1*ev0;
                float t4 = W4 * INV_SQ2;
                av2[0] = fmaf(t4, cr0, av2[0]); av2[1] = fmaf(t4, cr1, av2[1]); av2[2] = fmaf(t4, cr2, av2[2]);
            }
            WAVE_SYNC();
        }

        // ---- epilogue: combine halves, project through W20/W21, RMW out ----
        a0 += __shfl_xor(a0, 32, 64);
        a1 += __shfl_xor(a1, 32, 64);
        #pragma unroll
        for (int i = 0; i < 3; i++) {
            av0[i] += __shfl_xor(av0[i], 32, 64);
            av1[i] += __shfl_xor(av1[i], 32, 64);
            av2[i] += __shfl_xor(av2[i], 32, 64);
        }
        float* sc = &sH[wave][0][0];     // 512 floats scratch, need 352
        if (half == 0) {
            sc[u] = a0; sc[32+u] = a1;
            #pragma unroll
            for (int i = 0; i < 3; i++) {
                sc[64 + 3*u + i]        = av0[i];   // node_v rows 0..31 (mid2)
                sc[64 + 96 + 3*u + i]   = av1[i];   // rows 32..63      (mid3)
                sc[64 + 192 + 3*u + i]  = av2[i];   // rows 64..95      (mid4)
            }
        }
        WAVE_SYNC();

        float gs = C_X * na * INV_SQRT_NN * INV8;
        float gv = C_X * na * INV_SQRT_NN * INV_SQ96;
        #pragma unroll
        for (int p = 0; p < 2; p++) {
            int o = lane + p*64;
            float val = 0.f;
            if (o < 32) {
                #pragma unroll 8
                for (int k = 0; k < 64; k++) val = fmaf(sc[k], W20[k*32 + o], val);
                out[(size_t)node*128 + o] += gs * val;
            } else {
                int f = o - 32; int w = f / 3; int i3 = f - 3*w;
                #pragma unroll 8
                for (int k = 0; k < 96; k++) val = fmaf(sc[64 + 3*k + i3], W21[k*32 + w], val);
                out[(size_t)node*128 + o] += gv * val;
            }
        }
        WAVE_SYNC();   // sc (sH) reuse guard before next group
    }
}

// ---------------- launch ----------------
extern "C" void kernel_launch(void* const* d_in, const int* in_sizes, int n_in,
                              void* d_out, int out_size, void* d_ws, size_t ws_size,
                              hipStream_t stream)
{
    const float* node_input   = (const float*)d_in[0];
    const float* node_attr    = (const float*)d_in[1];
    const int*   edge_index   = (const int*)  d_in[2];
    const float* edge_attr    = (const float*)d_in[3];
    const float* edge_scalars = (const float*)d_in[4];
    const float* W_sc0 = (const float*)d_in[5];
    const float* W_sc1 = (const float*)d_in[6];
    const float* W_l10 = (const float*)d_in[7];
    const float* W_l11 = (const float*)d_in[8];
    const float* Wfc0  = (const float*)d_in[9];
    const float* Wfc1  = (const float*)d_in[10];
    const float* W_l20 = (const float*)d_in[11];
    const float* W_l21 = (const float*)d_in[12];
    float* out = (float*)d_out;

    int N = in_sizes[1];        // node_attr: N x 1
    int E = in_sizes[2] / 2;    // edge_index: 2 x E

    // workspace layout (~23.6 MB)
    char* ws = (char*)d_ws;
    size_t off = 0;
    float* l_sv  = (float*)(ws + off); off += (size_t)N * 128 * 4;
    int*   deg   = (int*)  (ws + off); off += (size_t)N * 4;
    int*   cur   = (int*)  (ws + off); off += (size_t)N * 4;       // contiguous after deg
    int*   offs  = (int*)  (ws + off); off += ((size_t)N + 1) * 4;
    off = (off + 255) & ~(size_t)255;
    int*   elist = (int*)  (ws + off); off += (size_t)E * 4;
    int*   part  = (int*)  (ws + off); off += 64 * 4;

    hipMemsetAsync(deg, 0, (size_t)N * 2 * 4, stream);   // deg + cur

    int ngroups = (N + 3) / 4;
    int nb_node = ngroups < 1024 ? ngroups : 1024;
    k_node<<<nb_node, 256, 0, stream>>>(node_input, node_attr, W_sc0, W_sc1, W_l10, W_l11,
                                        out, l_sv, N);
    k_hist<<<(E + 255)/256, 256, 0, stream>>>(edge_index, deg, E);
    int nchunk = (N + 1023) / 1024;
    k_scan_part<<<nchunk, 1024, 0, stream>>>(deg, offs, part, N);
    k_scan_top<<<1, 64, 0, stream>>>(part, offs, nchunk, N);
    k_scan_add<<<(N + 255)/256, 256, 0, stream>>>(offs, part, N);
    k_fill<<<(E + 255)/256, 256, 0, stream>>>(edge_index, offs, cur, elist, E);
    int nb_edge = ngroups < 1536 ? ngroups : 1536;   // 2 resident batches at 3 blocks/CU
    k_edge<<<nb_edge, 256, 0, stream>>>(edge_index, edge_attr, edge_scalars,
                                        Wfc0, Wfc1, W_l20, W_l21,
                                        node_attr, l_sv, offs, elist, out, N, E);
}

// Round 7
// 692.011 us; speedup vs baseline: 1.0276x; 1.0276x over previous
//
#include <hip/hip_runtime.h>
#include <math.h>

static constexpr float F0        = 0.17677669529663687f;  // 1/sqrt(32)
static constexpr float SILU_GAIN = 1.6791f;
static constexpr float INV_SQ3   = 0.5773502691896258f;   // 1/sqrt(3)
static constexpr float INV_SQ2   = 0.7071067811865475f;   // 1/sqrt(2)
static constexpr float C_S       = 0.3826834323650898f;   // sin(pi/8)
static constexpr float C_X       = 0.9238795325112867f;   // cos(pi/8)
static constexpr float INV_SQRT_NN = 0.25f;
static constexpr float INV8      = 0.125f;                // 1/8 (and 1/sqrt(64))
static constexpr float INV_SQ96  = 0.10206207261596575f;  // 1/sqrt(96)

// Wave-synchronous LDS sync: program-order pin for the compiler (memory clobber)
// + scheduling barrier. Per-wave DS-pipe in-order execution provides the HW side.
#define WAVE_SYNC() do { asm volatile("" ::: "memory"); \
                         __builtin_amdgcn_wave_barrier(); \
                         asm volatile("" ::: "memory"); } while (0)

// ---------------- K1: per-node linear transforms (grid-strided) ----------------
__global__ __launch_bounds__(256) void k_node(
    const float* __restrict__ node_input, const float* __restrict__ node_attr,
    const float* __restrict__ Wsc0, const float* __restrict__ Wsc1,
    const float* __restrict__ Wl10, const float* __restrict__ Wl11,
    float* __restrict__ out, float* __restrict__ l_sv, int N)
{
    __shared__ float sW[4][32][32];          // Wsc0, Wsc1, Wl10, Wl11
    __shared__ __align__(16) float sX[4][128];
    int tid = threadIdx.x;
    float4* sWv = (float4*)&sW[0][0][0];
    for (int i = tid; i < 256; i += 256) {   // 1024 floats per matrix = 256 float4
        sWv[i]       = ((const float4*)Wsc0)[i];
        sWv[256+i]   = ((const float4*)Wsc1)[i];
        sWv[512+i]   = ((const float4*)Wl10)[i];
        sWv[768+i]   = ((const float4*)Wl11)[i];
    }
    __syncthreads();
    int wave = tid >> 6, lane = tid & 63;
    int ngroups = (N + 3) >> 2;

    for (int grp = blockIdx.x; grp < ngroups; grp += gridDim.x) {
        int node = grp * 4 + wave;
        if (node >= N) continue;

        float2 v = *(const float2*)&node_input[(size_t)node*128 + lane*2];
        sX[wave][lane*2]   = v.x;
        sX[wave][lane*2+1] = v.y;
        float na = node_attr[node];
        WAVE_SYNC();

        const float* X = sX[wave];
        float g = F0 * na;
        #pragma unroll
        for (int p = 0; p < 2; p++) {
            int o = lane + p*64;
            float vs = 0.f, vl = 0.f;
            if (o < 32) {
                #pragma unroll
                for (int u = 0; u < 32; u++) {
                    float x = X[u];
                    vs = fmaf(x, sW[0][u][o], vs);
                    vl = fmaf(x, sW[2][u][o], vl);
                }
            } else {
                int f = o - 32; int w = f / 3; int i3 = f - 3*w;
                #pragma unroll
                for (int u = 0; u < 32; u++) {
                    float x = X[32 + 3*u + i3];
                    vs = fmaf(x, sW[1][u][w], vs);
                    vl = fmaf(x, sW[3][u][w], vl);
                }
            }
            out [(size_t)node*128 + o] = C_S * g * vs;
            l_sv[(size_t)node*128 + o] = g * vl;
        }
        WAVE_SYNC();   // sX reuse guard
    }
}

// ---------------- CSR build ----------------
__global__ void k_hist(const int* __restrict__ ei, int* __restrict__ deg, int E) {
    int e = blockIdx.x*256 + threadIdx.x;
    if (e < E) atomicAdd(&deg[ei[E + e]], 1);
}

__global__ void k_scan_part(const int* __restrict__ deg, int* __restrict__ offs,
                            int* __restrict__ part, int n) {
    __shared__ int tmp[1024];
    int t = threadIdx.x, i = blockIdx.x*1024 + t;
    int v = (i < n) ? deg[i] : 0;
    tmp[t] = v; __syncthreads();
    for (int d = 1; d < 1024; d <<= 1) {
        int x = (t >= d) ? tmp[t-d] : 0;
        __syncthreads();
        tmp[t] += x;
        __syncthreads();
    }
    if (i < n) offs[i] = tmp[t] - v;           // block-local exclusive
    if (t == 1023) part[blockIdx.x] = tmp[1023];
}

__global__ void k_scan_top(int* part, int* offs, int nb, int n) {
    if (threadIdx.x == 0 && blockIdx.x == 0) {
        int run = 0;
        for (int b = 0; b < nb; b++) { int v = part[b]; part[b] = run; run += v; }
        offs[n] = run;                          // == E
    }
}

__global__ void k_scan_add(int* offs, const int* part, int n) {
    int i = blockIdx.x*256 + threadIdx.x;
    if (i < n) offs[i] += part[i >> 10];
}

__global__ void k_fill(const int* __restrict__ ei, const int* __restrict__ offs,
                       int* __restrict__ cur, int* __restrict__ elist, int E) {
    int e = blockIdx.x*256 + threadIdx.x;
    if (e < E) {
        int d = ei[E + e];
        int p = atomicAdd(&cur[d], 1);
        elist[offs[d] + p] = e;
    }
}

// ---------------- K2: wave-per-node edge aggregation (grid-strided) ----------------
// LDS 50.6KB -> 3 blocks/CU. Wfc0 in 16 VGPRs; W20/W21 from global (L1-resident).
// Chunk staging is software-pipelined: next chunk's mylist->edge-data dependent
// chain is issued into registers during the current chunk's ~4000cy of compute
// (T14 async-STAGE split), so only the first chunk per node pays gather latency.
__global__ __launch_bounds__(256, 3) void k_edge(
    const int*   __restrict__ ei,           // 2*E (src | dst)
    const float* __restrict__ edge_attr,    // E x 4
    const float* __restrict__ edge_scalars, // E x 16
    const float* __restrict__ Wfc0,         // 16 x 64
    const float* __restrict__ Wfc1,         // 64 x 160
    const float* __restrict__ W20,          // 64 x 32
    const float* __restrict__ W21,          // 96 x 32
    const float* __restrict__ node_attr,
    const float* __restrict__ l_sv,
    const int*   __restrict__ offs,
    const int*   __restrict__ elist,
    float* __restrict__ out, int N, int E)
{
    __shared__ float sWfc1[64][160];             // 40 KB  (col%32 -> 2 lanes/bank, free)
    __shared__ __align__(16) float sH [4][8][64];// 8 KB  (h per edge; reused as epilogue scratch)
    __shared__ __align__(16) float sES[4][8][16];// 2 KB
    __shared__ float sEA[4][8][4];
    __shared__ int   sSRC[4][8];

    int tid = threadIdx.x;
    {   // 10240 floats = 2560 float4
        float4* dst = (float4*)&sWfc1[0][0];
        const float4* src = (const float4*)Wfc1;
        for (int i = tid; i < 2560; i += 256) dst[i] = src[i];
    }

    int wave = tid >> 6, lane = tid & 63;
    int half = lane >> 5, u = lane & 31;

    // Wfc0 column for this lane: 16 registers, reused for every edge.
    float wfc0_r[16];
    #pragma unroll
    for (int i = 0; i < 16; i++) wfc0_r[i] = Wfc0[i*64 + lane];

    __syncthreads();

    int ngroups = (N + 3) >> 2;
    int es_e = lane >> 3, es_i2 = (lane & 7) << 1;   // edge_scalars staging role

    for (int grp = blockIdx.x; grp < ngroups; grp += gridDim.x) {
        int node = grp * 4 + wave;
        if (node >= N) continue;

        int e0 = offs[node], e1 = offs[node+1];
        int cnt_all = e1 - e0;
        const int* mylist = elist + e0;
        float na = node_attr[node];          // issued early: latency hides under edge loop

        float a0 = 0.f, a1 = 0.f;
        float av0[3] = {0,0,0}, av1[3] = {0,0,0}, av2[3] = {0,0,0};

        // ---- staging registers for the pipelined chunk loads ----
        int    r_src;   // lane<8: src node of edge (base+lane)
        float4 r_ea;    // lane<8: edge_attr of edge (base+lane)
        float2 r_es;    // all lanes: edge_scalars[es_e][es_i2..+1]
        #define STAGE_REGS(B) do {                                               \
            bool v8 = (lane < 8) && ((B) + lane < cnt_all);                      \
            int eidA = v8 ? mylist[(B) + lane] : 0;                              \
            r_src = v8 ? ei[eidA] : 0;                                           \
            r_ea  = v8 ? *(const float4*)&edge_attr[(size_t)eidA*4]              \
                       : make_float4(0.f,0.f,0.f,0.f);                           \
            bool ve = ((B) + es_e) < cnt_all;                                    \
            int eidB = ve ? mylist[(B) + es_e] : 0;                              \
            r_es = ve ? *(const float2*)&edge_scalars[(size_t)eidB*16 + es_i2]   \
                      : make_float2(0.f,0.f);                                    \
        } while (0)

        STAGE_REGS(0);   // prologue: first chunk pays the latency

        for (int base = 0; base < cnt_all; base += 8) {
            // ---- write staged regs to LDS ----
            if (lane < 8) {
                sSRC[wave][lane] = r_src;
                sEA[wave][lane][0] = r_ea.x; sEA[wave][lane][1] = r_ea.y;
                sEA[wave][lane][2] = r_ea.z; sEA[wave][lane][3] = r_ea.w;
            }
            sES[wave][es_e][es_i2]   = r_es.x;
            sES[wave][es_e][es_i2+1] = r_es.y;
            WAVE_SYNC();

            // ---- issue next chunk's staging NOW; latency hides under phases 1-3.
            // (regs are dead after the LDS writes above; predicated off past the end)
            STAGE_REGS(base + 8);

            // ---- gather prefetch: l_sv loads for this chunk, used in phase 3 ----
            float xs_r[4], xv_r[4][3];
            #pragma unroll
            for (int t = 0; t < 4; t++) {
                int srcn = sSRC[wave][half*4 + t];
                const float* lp = l_sv + (size_t)srcn * 128;
                xs_r[t]    = lp[u];
                xv_r[t][0] = lp[32 + 3*u];
                xv_r[t][1] = lp[33 + 3*u];
                xv_r[t][2] = lp[34 + 3*u];
            }

            // ---- phase 1: h[e][lane] = SILU_GAIN * silu(es@Wfc0 / 4) ----
            #pragma unroll
            for (int e = 0; e < 8; e++) {
                float s = 0.f;
                const float4* esv = (const float4*)sES[wave][e];
                #pragma unroll
                for (int i4 = 0; i4 < 4; i4++) {
                    float4 ev = esv[i4];
                    s = fmaf(ev.x, wfc0_r[i4*4+0], s);
                    s = fmaf(ev.y, wfc0_r[i4*4+1], s);
                    s = fmaf(ev.z, wfc0_r[i4*4+2], s);
                    s = fmaf(ev.w, wfc0_r[i4*4+3], s);
                }
                s *= 0.25f;
                sH[wave][e][lane] = SILU_GAIN * s / (1.f + __expf(-s));
            }
            WAVE_SYNC();

            // ---- phase 2: lane (half,u) computes w0..w4[u] for its 4 edges ----
            float w0[4] = {0,0,0,0}, w1[4] = {0,0,0,0}, w2[4] = {0,0,0,0};
            float w3[4] = {0,0,0,0}, w4[4] = {0,0,0,0};
            #pragma unroll 2
            for (int j = 0; j < 64; j += 4) {
                float4 hv0 = *(const float4*)&sH[wave][half*4+0][j];
                float4 hv1 = *(const float4*)&sH[wave][half*4+1][j];
                float4 hv2 = *(const float4*)&sH[wave][half*4+2][j];
                float4 hv3 = *(const float4*)&sH[wave][half*4+3][j];
                float h0[4] = {hv0.x, hv0.y, hv0.z, hv0.w};
                float h1[4] = {hv1.x, hv1.y, hv1.z, hv1.w};
                float h2[4] = {hv2.x, hv2.y, hv2.z, hv2.w};
                float h3[4] = {hv3.x, hv3.y, hv3.z, hv3.w};
                #pragma unroll
                for (int jj = 0; jj < 4; jj++) {
                    float c0 = sWfc1[j+jj][u];
                    float c1 = sWfc1[j+jj][32+u];
                    float c2 = sWfc1[j+jj][64+u];
                    float c3 = sWfc1[j+jj][96+u];
                    float c4 = sWfc1[j+jj][128+u];
                    w0[0]=fmaf(h0[jj],c0,w0[0]); w1[0]=fmaf(h0[jj],c1,w1[0]); w2[0]=fmaf(h0[jj],c2,w2[0]); w3[0]=fmaf(h0[jj],c3,w3[0]); w4[0]=fmaf(h0[jj],c4,w4[0]);
                    w0[1]=fmaf(h1[jj],c0,w0[1]); w1[1]=fmaf(h1[jj],c1,w1[1]); w2[1]=fmaf(h1[jj],c2,w2[1]); w3[1]=fmaf(h1[jj],c3,w3[1]); w4[1]=fmaf(h1[jj],c4,w4[1]);
                    w0[2]=fmaf(h2[jj],c0,w0[2]); w1[2]=fmaf(h2[jj],c1,w1[2]); w2[2]=fmaf(h2[jj],c2,w2[2]); w3[2]=fmaf(h2[jj],c3,w3[2]); w4[2]=fmaf(h2[jj],c4,w4[2]);
                    w0[3]=fmaf(h3[jj],c0,w0[3]); w1[3]=fmaf(h3[jj],c1,w1[3]); w2[3]=fmaf(h3[jj],c2,w2[3]); w3[3]=fmaf(h3[jj],c3,w3[3]); w4[3]=fmaf(h3[jj],c4,w4[3]);
                }
            }

            // ---- phase 3: mids + accumulate (invalid edges have w==0) ----
            #pragma unroll
            for (int t = 0; t < 4; t++) {
                int ee = half*4 + t;
                float ea0 = sEA[wave][ee][0];
                float ev0 = sEA[wave][ee][1], ev1 = sEA[wave][ee][2], ev2 = sEA[wave][ee][3];
                float xs  = xs_r[t];
                float xv0 = xv_r[t][0], xv1 = xv_r[t][1], xv2 = xv_r[t][2];
                float W0 = w0[t]*INV8, W1 = w1[t]*INV8, W2 = w2[t]*INV8;
                float W3 = w3[t]*INV8, W4 = w4[t]*INV8;

                a0 = fmaf(W0 * ea0, xs, a0);                       // mid0
                float dv = fmaf(xv0, ev0, fmaf(xv1, ev1, xv2*ev2));
                a1 = fmaf(W3 * INV_SQ3, dv, a1);                   // mid1
                float t1 = W1 * xs;                                 // mid2
                av0[0] = fmaf(t1, ev0, av0[0]); av0[1] = fmaf(t1, ev1, av0[1]); av0[2] = fmaf(t1, ev2, av0[2]);
                float t2 = W2 * ea0;                                // mid3
                av1[0] = fmaf(t2, xv0, av1[0]); av1[1] = fmaf(t2, xv1, av1[1]); av1[2] = fmaf(t2, xv2, av1[2]);
                float cr0 = xv1*ev2 - xv2*ev1;                      // mid4 (cross)
                float cr1 = xv2*ev0 - xv0*ev2;
                float cr2 = xv0*ev1 - xv1*ev0;
                float t4 = W4 * INV_SQ2;
                av2[0] = fmaf(t4, cr0, av2[0]); av2[1] = fmaf(t4, cr1, av2[1]); av2[2] = fmaf(t4, cr2, av2[2]);
            }
            WAVE_SYNC();
        }
        #undef STAGE_REGS

        // ---- epilogue: combine halves, project through W20/W21, RMW out ----
        a0 += __shfl_xor(a0, 32, 64);
        a1 += __shfl_xor(a1, 32, 64);
        #pragma unroll
        for (int i = 0; i < 3; i++) {
            av0[i] += __shfl_xor(av0[i], 32, 64);
            av1[i] += __shfl_xor(av1[i], 32, 64);
            av2[i] += __shfl_xor(av2[i], 32, 64);
        }
        float* sc = &sH[wave][0][0];     // 512 floats scratch, need 352
        if (half == 0) {
            sc[u] = a0; sc[32+u] = a1;
            #pragma unroll
            for (int i = 0; i < 3; i++) {
                sc[64 + 3*u + i]        = av0[i];   // node_v rows 0..31 (mid2)
                sc[64 + 96 + 3*u + i]   = av1[i];   // rows 32..63      (mid3)
                sc[64 + 192 + 3*u + i]  = av2[i];   // rows 64..95      (mid4)
            }
        }
        WAVE_SYNC();

        float gs = C_X * na * INV_SQRT_NN * INV8;
        float gv = C_X * na * INV_SQRT_NN * INV_SQ96;
        #pragma unroll
        for (int p = 0; p < 2; p++) {
            int o = lane + p*64;
            float val = 0.f;
            if (o < 32) {
                #pragma unroll 8
                for (int k = 0; k < 64; k++) val = fmaf(sc[k], W20[k*32 + o], val);
                out[(size_t)node*128 + o] += gs * val;
            } else {
                int f = o - 32; int w = f / 3; int i3 = f - 3*w;
                #pragma unroll 8
                for (int k = 0; k < 96; k++) val = fmaf(sc[64 + 3*k + i3], W21[k*32 + w], val);
                out[(size_t)node*128 + o] += gv * val;
            }
        }
        WAVE_SYNC();   // sc (sH) reuse guard before next group
    }
}

// ---------------- launch ----------------
extern "C" void kernel_launch(void* const* d_in, const int* in_sizes, int n_in,
                              void* d_out, int out_size, void* d_ws, size_t ws_size,
                              hipStream_t stream)
{
    const float* node_input   = (const float*)d_in[0];
    const float* node_attr    = (const float*)d_in[1];
    const int*   edge_index   = (const int*)  d_in[2];
    const float* edge_attr    = (const float*)d_in[3];
    const float* edge_scalars = (const float*)d_in[4];
    const float* W_sc0 = (const float*)d_in[5];
    const float* W_sc1 = (const float*)d_in[6];
    const float* W_l10 = (const float*)d_in[7];
    const float* W_l11 = (const float*)d_in[8];
    const float* Wfc0  = (const float*)d_in[9];
    const float* Wfc1  = (const float*)d_in[10];
    const float* W_l20 = (const float*)d_in[11];
    const float* W_l21 = (const float*)d_in[12];
    float* out = (float*)d_out;

    int N = in_sizes[1];        // node_attr: N x 1
    int E = in_sizes[2] / 2;    // edge_index: 2 x E

    // workspace layout (~23.6 MB)
    char* ws = (char*)d_ws;
    size_t off = 0;
    float* l_sv  = (float*)(ws + off); off += (size_t)N * 128 * 4;
    int*   deg   = (int*)  (ws + off); off += (size_t)N * 4;
    int*   cur   = (int*)  (ws + off); off += (size_t)N * 4;       // contiguous after deg
    int*   offs  = (int*)  (ws + off); off += ((size_t)N + 1) * 4;
    off = (off + 255) & ~(size_t)255;
    int*   elist = (int*)  (ws + off); off += (size_t)E * 4;
    int*   part  = (int*)  (ws + off); off += 64 * 4;

    hipMemsetAsync(deg, 0, (size_t)N * 2 * 4, stream);   // deg + cur

    int ngroups = (N + 3) / 4;
    int nb_node = ngroups < 1024 ? ngroups : 1024;
    k_node<<<nb_node, 256, 0, stream>>>(node_input, node_attr, W_sc0, W_sc1, W_l10, W_l11,
                                        out, l_sv, N);
    k_hist<<<(E + 255)/256, 256, 0, stream>>>(edge_index, deg, E);
    int nchunk = (N + 1023) / 1024;
    k_scan_part<<<nchunk, 1024, 0, stream>>>(deg, offs, part, N);
    k_scan_top<<<1, 64, 0, stream>>>(part, offs, nchunk, N);
    k_scan_add<<<(N + 255)/256, 256, 0, stream>>>(offs, part, N);
    k_fill<<<(E + 255)/256, 256, 0, stream>>>(edge_index, offs, cur, elist, E);
    int nb_edge = ngroups < 1536 ? ngroups : 1536;   // 2 resident batches at 3 blocks/CU
    k_edge<<<nb_edge, 256, 0, stream>>>(edge_index, edge_attr, edge_scalars,
                                        Wfc0, Wfc1, W_l20, W_l21,
                                        node_attr, l_sv, offs, elist, out, N, E);
}

// Round 8
// 669.031 us; speedup vs baseline: 1.0629x; 1.0343x over previous
//
#include <hip/hip_runtime.h>
#include <math.h>

static constexpr float F0        = 0.17677669529663687f;  // 1/sqrt(32)
static constexpr float SILU_GAIN = 1.6791f;
static constexpr float INV_SQ3   = 0.5773502691896258f;   // 1/sqrt(3)
static constexpr float INV_SQ2   = 0.7071067811865475f;   // 1/sqrt(2)
static constexpr float C_S       = 0.3826834323650898f;   // sin(pi/8)
static constexpr float C_X       = 0.9238795325112867f;   // cos(pi/8)
static constexpr float INV_SQRT_NN = 0.25f;
static constexpr float INV8      = 0.125f;                // 1/8 (and 1/sqrt(64))
static constexpr float INV_SQ96  = 0.10206207261596575f;  // 1/sqrt(96)

#define WAVE_SYNC() do { asm volatile("" ::: "memory"); \
                         __builtin_amdgcn_wave_barrier(); \
                         asm volatile("" ::: "memory"); } while (0)

// ---------------- K1: per-node linear transforms (grid-strided) ----------------
__global__ __launch_bounds__(256) void k_node(
    const float* __restrict__ node_input, const float* __restrict__ node_attr,
    const float* __restrict__ Wsc0, const float* __restrict__ Wsc1,
    const float* __restrict__ Wl10, const float* __restrict__ Wl11,
    float* __restrict__ out, float* __restrict__ l_sv, int N)
{
    __shared__ float sW[4][32][32];          // Wsc0, Wsc1, Wl10, Wl11
    __shared__ __align__(16) float sX[4][128];
    int tid = threadIdx.x;
    float4* sWv = (float4*)&sW[0][0][0];
    for (int i = tid; i < 256; i += 256) {
        sWv[i]       = ((const float4*)Wsc0)[i];
        sWv[256+i]   = ((const float4*)Wsc1)[i];
        sWv[512+i]   = ((const float4*)Wl10)[i];
        sWv[768+i]   = ((const float4*)Wl11)[i];
    }
    __syncthreads();
    int wave = tid >> 6, lane = tid & 63;
    int ngroups = (N + 3) >> 2;

    for (int grp = blockIdx.x; grp < ngroups; grp += gridDim.x) {
        int node = grp * 4 + wave;
        if (node >= N) continue;

        float2 v = *(const float2*)&node_input[(size_t)node*128 + lane*2];
        sX[wave][lane*2]   = v.x;
        sX[wave][lane*2+1] = v.y;
        float na = node_attr[node];
        WAVE_SYNC();

        const float* X = sX[wave];
        float g = F0 * na;
        #pragma unroll
        for (int p = 0; p < 2; p++) {
            int o = lane + p*64;
            float vs = 0.f, vl = 0.f;
            if (o < 32) {
                #pragma unroll
                for (int u = 0; u < 32; u++) {
                    float x = X[u];
                    vs = fmaf(x, sW[0][u][o], vs);
                    vl = fmaf(x, sW[2][u][o], vl);
                }
            } else {
                int f = o - 32; int w = f / 3; int i3 = f - 3*w;
                #pragma unroll
                for (int u = 0; u < 32; u++) {
                    float x = X[32 + 3*u + i3];
                    vs = fmaf(x, sW[1][u][w], vs);
                    vl = fmaf(x, sW[3][u][w], vl);
                }
            }
            out [(size_t)node*128 + o] = C_S * g * vs;
            l_sv[(size_t)node*128 + o] = g * vl;
        }
        WAVE_SYNC();   // sX reuse guard
    }
}

// ---------------- CSR build ----------------
__global__ void k_hist(const int* __restrict__ ei, int* __restrict__ deg, int E) {
    int e = blockIdx.x*256 + threadIdx.x;
    if (e < E) atomicAdd(&deg[ei[E + e]], 1);
}

__global__ void k_scan_part(const int* __restrict__ deg, int* __restrict__ offs,
                            int* __restrict__ part, int n) {
    __shared__ int tmp[1024];
    int t = threadIdx.x, i = blockIdx.x*1024 + t;
    int v = (i < n) ? deg[i] : 0;
    tmp[t] = v; __syncthreads();
    for (int d = 1; d < 1024; d <<= 1) {
        int x = (t >= d) ? tmp[t-d] : 0;
        __syncthreads();
        tmp[t] += x;
        __syncthreads();
    }
    if (i < n) offs[i] = tmp[t] - v;           // block-local exclusive
    if (t == 1023) part[blockIdx.x] = tmp[1023];
}

__global__ void k_scan_top(int* part, int nb) {
    if (threadIdx.x == 0 && blockIdx.x == 0) {
        int run = 0;
        for (int b = 0; b < nb; b++) { int v = part[b]; part[b] = run; run += v; }
    }
}

// global offset of node d = offs[d] (block-local) + part[d>>10]
__global__ void k_fill(const int* __restrict__ ei, const int* __restrict__ offs,
                       const int* __restrict__ part,
                       int* __restrict__ cur, int* __restrict__ elist, int E) {
    int e = blockIdx.x*256 + threadIdx.x;
    if (e < E) {
        int d = ei[E + e];
        int p = atomicAdd(&cur[d], 1);
        elist[offs[d] + part[d >> 10] + p] = e;
    }
}

// ---------------- K2: wave-per-node edge aggregation (grid-strided) ----------------
// LDS 50.6KB -> 3 blocks/CU. Wfc0 in 16 VGPRs; W20/W21 from global (L1-resident).
// Wfc1 stored TRANSPOSED + XOR-swizzled in LDS: element (row j, col c) lives at
// sWfc1T[c][ 2*((j>>1) ^ (c&31)) + (j&1) ]  -> phase-2 reads are float2 (b64),
// 2-way bank aliasing only (free), 160 DS reads/chunk instead of 320.
__global__ __launch_bounds__(256, 3) void k_edge(
    const int*   __restrict__ ei,           // 2*E (src | dst)
    const float* __restrict__ edge_attr,    // E x 4
    const float* __restrict__ edge_scalars, // E x 16
    const float* __restrict__ Wfc0,         // 16 x 64
    const float* __restrict__ Wfc1,         // 64 x 160
    const float* __restrict__ W20,          // 64 x 32
    const float* __restrict__ W21,          // 96 x 32
    const float* __restrict__ node_attr,
    const float* __restrict__ l_sv,
    const int*   __restrict__ offs,
    const int*   __restrict__ part,
    const int*   __restrict__ elist,
    float* __restrict__ out, int N, int E)
{
    __shared__ float sWfc1T[160][64];            // 40 KB (transposed + swizzled)
    __shared__ __align__(16) float sH [4][8][64];// 8 KB  (h per edge; epilogue scratch)
    __shared__ __align__(16) float sES[4][8][16];// 2 KB
    __shared__ float sEA[4][8][4];
    __shared__ int   sSRC[4][8];

    int tid = threadIdx.x;
    // transpose+swizzle Wfc1 into LDS (once per block; coalesced global reads)
    for (int idx = tid; idx < 10240; idx += 256) {
        int j = idx / 160, c = idx - 160*j;       // Wfc1[j][c]
        sWfc1T[c][2*(((j>>1)) ^ (c & 31)) + (j & 1)] = Wfc1[idx];
    }

    int wave = tid >> 6, lane = tid & 63;
    int half = lane >> 5, u = lane & 31;

    // Wfc0 column for this lane: 16 registers, reused for every edge.
    float wfc0_r[16];
    #pragma unroll
    for (int i = 0; i < 16; i++) wfc0_r[i] = Wfc0[i*64 + lane];

    __syncthreads();

    int ngroups = (N + 3) >> 2;
    int es_e = lane >> 3, es_i2 = (lane & 7) << 1;   // edge_scalars staging role

    for (int grp = blockIdx.x; grp < ngroups; grp += gridDim.x) {
        int node = grp * 4 + wave;
        if (node >= N) continue;

        int e0 = offs[node] + part[node >> 10];
        int e1 = (node + 1 < N) ? (offs[node+1] + part[(node+1) >> 10]) : E;
        int cnt_all = e1 - e0;
        const int* mylist = elist + e0;
        float na = node_attr[node];          // early: latency hides under edge loop

        float a0 = 0.f, a1 = 0.f;
        float av0[3] = {0,0,0}, av1[3] = {0,0,0}, av2[3] = {0,0,0};

        int    r_src;   // lane<8: src node of edge (base+lane)
        float4 r_ea;    // lane<8: edge_attr of edge (base+lane)
        float2 r_es;    // all lanes: edge_scalars[es_e][es_i2..+1]
        #define STAGE_REGS(B) do {                                               \
            bool v8 = (lane < 8) && ((B) + lane < cnt_all);                      \
            int eidA = v8 ? mylist[(B) + lane] : 0;                              \
            r_src = v8 ? ei[eidA] : 0;                                           \
            r_ea  = v8 ? *(const float4*)&edge_attr[(size_t)eidA*4]              \
                       : make_float4(0.f,0.f,0.f,0.f);                           \
            bool ve = ((B) + es_e) < cnt_all;                                    \
            int eidB = ve ? mylist[(B) + es_e] : 0;                              \
            r_es = ve ? *(const float2*)&edge_scalars[(size_t)eidB*16 + es_i2]   \
                      : make_float2(0.f,0.f);                                    \
        } while (0)

        STAGE_REGS(0);

        for (int base = 0; base < cnt_all; base += 8) {
            // ---- write staged regs to LDS ----
            if (lane < 8) {
                sSRC[wave][lane] = r_src;
                sEA[wave][lane][0] = r_ea.x; sEA[wave][lane][1] = r_ea.y;
                sEA[wave][lane][2] = r_ea.z; sEA[wave][lane][3] = r_ea.w;
            }
            sES[wave][es_e][es_i2]   = r_es.x;
            sES[wave][es_e][es_i2+1] = r_es.y;
            WAVE_SYNC();

            // ---- issue next chunk's staging; hides under phases 1-3 ----
            STAGE_REGS(base + 8);

            // ---- gather prefetch: l_sv loads for this chunk, used in phase 3 ----
            float xs_r[4], xv_r[4][3];
            #pragma unroll
            for (int t = 0; t < 4; t++) {
                int srcn = sSRC[wave][half*4 + t];
                const float* lp = l_sv + (size_t)srcn * 128;
                xs_r[t] = lp[u];
                float3 v3 = *(const float3*)&lp[32 + 3*u];   // dwordx3
                xv_r[t][0] = v3.x; xv_r[t][1] = v3.y; xv_r[t][2] = v3.z;
            }

            // ---- phase 1: h[e][lane] = SILU_GAIN * silu(es@Wfc0 / 4) ----
            #pragma unroll
            for (int e = 0; e < 8; e++) {
                float s = 0.f;
                const float4* esv = (const float4*)sES[wave][e];
                #pragma unroll
                for (int i4 = 0; i4 < 4; i4++) {
                    float4 ev = esv[i4];
                    s = fmaf(ev.x, wfc0_r[i4*4+0], s);
                    s = fmaf(ev.y, wfc0_r[i4*4+1], s);
                    s = fmaf(ev.z, wfc0_r[i4*4+2], s);
                    s = fmaf(ev.w, wfc0_r[i4*4+3], s);
                }
                s *= 0.25f;
                sH[wave][e][lane] = SILU_GAIN * s * __builtin_amdgcn_rcpf(1.f + __expf(-s));
            }
            WAVE_SYNC();

            // ---- phase 2: lane (half,u) computes w0..w4[u] for its 4 edges ----
            float w0[4] = {0,0,0,0}, w1[4] = {0,0,0,0}, w2[4] = {0,0,0,0};
            float w3[4] = {0,0,0,0}, w4[4] = {0,0,0,0};
            #pragma unroll 2
            for (int jb4 = 0; jb4 < 16; jb4++) {
                int j = jb4 * 4;
                float4 hv0 = *(const float4*)&sH[wave][half*4+0][j];
                float4 hv1 = *(const float4*)&sH[wave][half*4+1][j];
                float4 hv2 = *(const float4*)&sH[wave][half*4+2][j];
                float4 hv3 = *(const float4*)&sH[wave][half*4+3][j];
                float h0[4] = {hv0.x, hv0.y, hv0.z, hv0.w};
                float h1[4] = {hv1.x, hv1.y, hv1.z, hv1.w};
                float h2[4] = {hv2.x, hv2.y, hv2.z, hv2.w};
                float h3[4] = {hv3.x, hv3.y, hv3.z, hv3.w};
                // weight rows j..j+3 for cols q*32+u, from transposed/swizzled LDS
                float c[5][4];
                int b0 = (2*jb4) ^ u, b1 = (2*jb4 + 1) ^ u;
                #pragma unroll
                for (int q = 0; q < 5; q++) {
                    const float* Tc = &sWfc1T[q*32 + u][0];
                    float2 f2a = *(const float2*)&Tc[2*b0];
                    float2 f2b = *(const float2*)&Tc[2*b1];
                    c[q][0] = f2a.x; c[q][1] = f2a.y; c[q][2] = f2b.x; c[q][3] = f2b.y;
                }
                #pragma unroll
                for (int jj = 0; jj < 4; jj++) {
                    float c0 = c[0][jj], c1 = c[1][jj], c2 = c[2][jj], c3 = c[3][jj], c4 = c[4][jj];
                    w0[0]=fmaf(h0[jj],c0,w0[0]); w1[0]=fmaf(h0[jj],c1,w1[0]); w2[0]=fmaf(h0[jj],c2,w2[0]); w3[0]=fmaf(h0[jj],c3,w3[0]); w4[0]=fmaf(h0[jj],c4,w4[0]);
                    w0[1]=fmaf(h1[jj],c0,w0[1]); w1[1]=fmaf(h1[jj],c1,w1[1]); w2[1]=fmaf(h1[jj],c2,w2[1]); w3[1]=fmaf(h1[jj],c3,w3[1]); w4[1]=fmaf(h1[jj],c4,w4[1]);
                    w0[2]=fmaf(h2[jj],c0,w0[2]); w1[2]=fmaf(h2[jj],c1,w1[2]); w2[2]=fmaf(h2[jj],c2,w2[2]); w3[2]=fmaf(h2[jj],c3,w3[2]); w4[2]=fmaf(h2[jj],c4,w4[2]);
                    w0[3]=fmaf(h3[jj],c0,w0[3]); w1[3]=fmaf(h3[jj],c1,w1[3]); w2[3]=fmaf(h3[jj],c2,w2[3]); w3[3]=fmaf(h3[jj],c3,w3[3]); w4[3]=fmaf(h3[jj],c4,w4[3]);
                }
            }

            // ---- phase 3: mids + accumulate (invalid edges have w==0) ----
            #pragma unroll
            for (int t = 0; t < 4; t++) {
                int ee = half*4 + t;
                float ea0 = sEA[wave][ee][0];
                float ev0 = sEA[wave][ee][1], ev1 = sEA[wave][ee][2], ev2 = sEA[wave][ee][3];
                float xs  = xs_r[t];
                float xv0 = xv_r[t][0], xv1 = xv_r[t][1], xv2 = xv_r[t][2];
                float W0 = w0[t]*INV8, W1 = w1[t]*INV8, W2 = w2[t]*INV8;
                float W3 = w3[t]*INV8, W4 = w4[t]*INV8;

                a0 = fmaf(W0 * ea0, xs, a0);                       // mid0
                float dv = fmaf(xv0, ev0, fmaf(xv1, ev1, xv2*ev2));
                a1 = fmaf(W3 * INV_SQ3, dv, a1);                   // mid1
                float t1 = W1 * xs;                                 // mid2
                av0[0] = fmaf(t1, ev0, av0[0]); av0[1] = fmaf(t1, ev1, av0[1]); av0[2] = fmaf(t1, ev2, av0[2]);
                float t2 = W2 * ea0;                                // mid3
                av1[0] = fmaf(t2, xv0, av1[0]); av1[1] = fmaf(t2, xv1, av1[1]); av1[2] = fmaf(t2, xv2, av1[2]);
                float cr0 = xv1*ev2 - xv2*ev1;                      // mid4 (cross)
                float cr1 = xv2*ev0 - xv0*ev2;
                float cr2 = xv0*ev1 - xv1*ev0;
                float t4 = W4 * INV_SQ2;
                av2[0] = fmaf(t4, cr0, av2[0]); av2[1] = fmaf(t4, cr1, av2[1]); av2[2] = fmaf(t4, cr2, av2[2]);
            }
            WAVE_SYNC();
        }
        #undef STAGE_REGS

        // ---- epilogue: combine halves, project through W20/W21, RMW out ----
        a0 += __shfl_xor(a0, 32, 64);
        a1 += __shfl_xor(a1, 32, 64);
        #pragma unroll
        for (int i = 0; i < 3; i++) {
            av0[i] += __shfl_xor(av0[i], 32, 64);
            av1[i] += __shfl_xor(av1[i], 32, 64);
            av2[i] += __shfl_xor(av2[i], 32, 64);
        }
        float* sc = &sH[wave][0][0];     // 512 floats scratch, need 352
        if (half == 0) {
            sc[u] = a0; sc[32+u] = a1;
            #pragma unroll
            for (int i = 0; i < 3; i++) {
                sc[64 + 3*u + i]        = av0[i];   // node_v rows 0..31 (mid2)
                sc[64 + 96 + 3*u + i]   = av1[i];   // rows 32..63      (mid3)
                sc[64 + 192 + 3*u + i]  = av2[i];   // rows 64..95      (mid4)
            }
        }
        WAVE_SYNC();

        float gs = C_X * na * INV_SQRT_NN * INV8;
        float gv = C_X * na * INV_SQRT_NN * INV_SQ96;
        #pragma unroll
        for (int p = 0; p < 2; p++) {
            int o = lane + p*64;
            float val = 0.f;
            if (o < 32) {
                #pragma unroll 8
                for (int k = 0; k < 64; k++) val = fmaf(sc[k], W20[k*32 + o], val);
                out[(size_t)node*128 + o] += gs * val;
            } else {
                int f = o - 32; int w = f / 3; int i3 = f - 3*w;
                #pragma unroll 8
                for (int k = 0; k < 96; k++) val = fmaf(sc[64 + 3*k + i3], W21[k*32 + w], val);
                out[(size_t)node*128 + o] += gv * val;
            }
        }
        WAVE_SYNC();   // sc (sH) reuse guard before next group
    }
}

// ---------------- launch ----------------
extern "C" void kernel_launch(void* const* d_in, const int* in_sizes, int n_in,
                              void* d_out, int out_size, void* d_ws, size_t ws_size,
                              hipStream_t stream)
{
    const float* node_input   = (const float*)d_in[0];
    const float* node_attr    = (const float*)d_in[1];
    const int*   edge_index   = (const int*)  d_in[2];
    const float* edge_attr    = (const float*)d_in[3];
    const float* edge_scalars = (const float*)d_in[4];
    const float* W_sc0 = (const float*)d_in[5];
    const float* W_sc1 = (const float*)d_in[6];
    const float* W_l10 = (const float*)d_in[7];
    const float* W_l11 = (const float*)d_in[8];
    const float* Wfc0  = (const float*)d_in[9];
    const float* Wfc1  = (const float*)d_in[10];
    const float* W_l20 = (const float*)d_in[11];
    const float* W_l21 = (const float*)d_in[12];
    float* out = (float*)d_out;

    int N = in_sizes[1];        // node_attr: N x 1
    int E = in_sizes[2] / 2;    // edge_index: 2 x E

    // workspace layout (~23.6 MB)
    char* ws = (char*)d_ws;
    size_t off = 0;
    float* l_sv  = (float*)(ws + off); off += (size_t)N * 128 * 4;
    int*   deg   = (int*)  (ws + off); off += (size_t)N * 4;
    int*   cur   = (int*)  (ws + off); off += (size_t)N * 4;       // contiguous after deg
    int*   offs  = (int*)  (ws + off); off += ((size_t)N + 1) * 4;
    off = (off + 255) & ~(size_t)255;
    int*   elist = (int*)  (ws + off); off += (size_t)E * 4;
    int*   part  = (int*)  (ws + off); off += 64 * 4;

    hipMemsetAsync(deg, 0, (size_t)N * 2 * 4, stream);   // deg + cur

    int ngroups = (N + 3) / 4;
    int nb_node = ngroups < 1024 ? ngroups : 1024;
    k_node<<<nb_node, 256, 0, stream>>>(node_input, node_attr, W_sc0, W_sc1, W_l10, W_l11,
                                        out, l_sv, N);
    k_hist<<<(E + 255)/256, 256, 0, stream>>>(edge_index, deg, E);
    int nchunk = (N + 1023) / 1024;
    k_scan_part<<<nchunk, 1024, 0, stream>>>(deg, offs, part, N);
    k_scan_top<<<1, 64, 0, stream>>>(part, nchunk);
    k_fill<<<(E + 255)/256, 256, 0, stream>>>(edge_index, offs, part, cur, elist, E);
    int nb_edge = ngroups < 1536 ? ngroups : 1536;   // 2 resident batches at 3 blocks/CU
    k_edge<<<nb_edge, 256, 0, stream>>>(edge_index, edge_attr, edge_scalars,
                                        Wfc0, Wfc1, W_l20, W_l21,
                                        node_attr, l_sv, offs, part, elist, out, N, E);
}